// Round 9
// baseline (790.977 us; speedup 1.0000x reference)
//
#include <hip/hip_runtime.h>
#include <math.h>

#define T_LEN   16384
#define NB      2
#define FCH     80
#define NLAYERS 24
#define TFRAMES 68
#define PAD     76

typedef __attribute__((ext_vector_type(8))) short bf16x8;
typedef __attribute__((ext_vector_type(4))) float f32x4;

static __device__ inline unsigned short f2bf(float f) {
    unsigned int u = __float_as_uint(f);
    unsigned int r = (u + 0x7FFFu + ((u >> 16) & 1u)) >> 16;
    return (unsigned short)r;
}

// ---------------------------------------------------------------------------
// Pack: bf16 weight layouts + firstWT (transposed embedding table, bias folded)
// ---------------------------------------------------------------------------
__global__ void k_pack(const float* __restrict__ convW, const float* __restrict__ condW,
                       const float* __restrict__ skipW, const float* __restrict__ resW,
                       const float* __restrict__ last1W, const float* __restrict__ last2W,
                       const float* __restrict__ firstW, const float* __restrict__ firstb,
                       unsigned short* __restrict__ ATb, unsigned short* __restrict__ SRTb,
                       unsigned short* __restrict__ W1b, unsigned short* __restrict__ W2b,
                       float* __restrict__ firstWT) {
    int idx = blockIdx.x * 256 + threadIdx.x;
    const int nAT = NLAYERS * 128 * 288;
    const int nSR = NLAYERS * 128 * 64;
    const int e0 = nAT, e1 = e0 + nSR, e2 = e1 + 4096, e3 = e2 + 16384, e4 = e3 + 16384;
    if (idx < e0) {
        int k = idx % 288;
        int o = (idx / 288) & 127;
        int l = idx / (288 * 128);
        float v = 0.f;
        if (k < 192) v = convW[(((l * 128 + o) * 64) + (k & 63)) * 3 + (k >> 6)];
        else if (k - 192 < 80) v = condW[(l * 128 + o) * 80 + (k - 192)];
        ATb[idx] = f2bf(v);
    } else if (idx < e1) {
        int j = idx - e0;
        int k = j & 63;
        int o2 = (j >> 6) & 127;
        int l = j / (64 * 128);
        float v = (o2 < 64) ? skipW[(l * 64 + o2) * 64 + k]
                            : resW[(l * 64 + (o2 - 64)) * 64 + k];
        SRTb[j] = f2bf(v);
    } else if (idx < e2) {
        W1b[idx - e1] = f2bf(last1W[idx - e1]);
    } else if (idx < e3) {
        W2b[idx - e2] = f2bf(last2W[idx - e2]);
    } else if (idx < e4) {
        int j = idx - e3;
        int xs = j >> 6, c = j & 63;
        firstWT[j] = firstW[c * 256 + xs] + firstb[c];
    }
}

// ---------------------------------------------------------------------------
// ConvIn: valid conv, kernel 5, (B,80,68) -> (B,80,64)
// ---------------------------------------------------------------------------
__global__ void k_convin(const float* __restrict__ feat, const float* __restrict__ W,
                         float* __restrict__ f0) {
    int idx = blockIdx.x * 256 + threadIdx.x;
    if (idx >= NB * FCH * 64) return;
    int t = idx & 63;
    int o = (idx >> 6) % FCH;
    int b = idx / (64 * FCH);
    const float* fb = feat + b * FCH * TFRAMES;
    const float* wo = W + o * FCH * 5;
    float acc = 0.f;
    for (int i = 0; i < FCH; ++i) {
        const float* fi = fb + i * TFRAMES + t;
        const float* wi = wo + i * 5;
#pragma unroll
        for (int k = 0; k < 5; ++k) acc += fi[k] * wi[k];
    }
    f0[idx] = acc;
}

// ---------------------------------------------------------------------------
// Upsample stage (x4 repeat + 9-tap smooth), fp32 c-major
// ---------------------------------------------------------------------------
__global__ void k_up(const float* __restrict__ in, float* __restrict__ out,
                     const float* __restrict__ kern, int Tin) {
    int Tout = Tin * 4;
    int idx = blockIdx.x * 256 + threadIdx.x;
    if (idx >= NB * FCH * Tout) return;
    int t = idx % Tout;
    int bc = idx / Tout;
    const float* ib = in + bc * Tin;
    float acc = 0.f;
#pragma unroll
    for (int k = 0; k < 9; ++k) {
        int u = t + k - 4;
        if (u >= 0 && u < Tout) acc += kern[k] * ib[u >> 2];
    }
    out[idx] = acc;
}

// ---------------------------------------------------------------------------
// Last upsample -> bf16 TIME-MAJOR [b][t][96], LDS-staged source frames
// ---------------------------------------------------------------------------
__global__ __launch_bounds__(256)
void k_up_last(const float* __restrict__ in, unsigned short* __restrict__ outH,
               const float* __restrict__ kern) {
    __shared__ float sF[18 * 80];
    const int tid = threadIdx.x;
    const int b  = blockIdx.x >> 8;
    const int t0 = (blockIdx.x & 255) * 64;
    const int fr0 = (t0 >> 2) - 1;

    for (int idx = tid; idx < 18 * 80; idx += 256) {
        int c = idx / 18, fr = idx - c * 18;
        int gfr = fr0 + fr;
        float v = 0.f;
        if (gfr >= 0 && gfr < 4096) v = in[((size_t)b * 80 + c) * 4096 + gfr];
        sF[fr * 80 + c] = v;
    }
    float kr[9];
#pragma unroll
    for (int k = 0; k < 9; ++k) kr[k] = kern[k];
    __syncthreads();

    for (int idx = tid; idx < 64 * 96; idx += 256) {
        int c = idx % 96;
        int t = idx / 96;
        float acc = 0.f;
        if (c < 80) {
            int ubase = t0 + t - 4;
#pragma unroll
            for (int k = 0; k < 9; ++k) {
                int fr = ((ubase + k) >> 2) - fr0;
                acc += kr[k] * sF[fr * 80 + c];
            }
        }
        outH[((size_t)b * T_LEN + t0 + t) * 96 + c] = f2bf(acc);
    }
}

// ---------------------------------------------------------------------------
// STACK KERNEL v3: single LDS residual buffer (in-place GEMM2 update) ->
// 79 KB LDS -> 2 blocks/CU (16 waves). Pad 76 (bank-conflict-free-ish).
// GEMM2 rebalanced: skip waves also do halo-res. 512 thr, tile 128, halo 128.
// flags: bit0 = first stack, bit1 = last stack
// ---------------------------------------------------------------------------
__global__ __launch_bounds__(512, 4)
void k_stack(const int* __restrict__ x, const float* __restrict__ firstWT,
             const float* __restrict__ prevF, const unsigned short* __restrict__ prevH,
             float* __restrict__ nextF, unsigned short* __restrict__ nextH,
             float* __restrict__ skipF, const unsigned short* __restrict__ ffb,
             const unsigned short* __restrict__ ATb, const unsigned short* __restrict__ SRTb,
             const float* __restrict__ convB, const float* __restrict__ skipB,
             const float* __restrict__ resB,
             const unsigned short* __restrict__ W1b, const float* __restrict__ b1,
             const unsigned short* __restrict__ W2b, const float* __restrict__ b2,
             float* __restrict__ outp, int flags)
{
    __shared__ __align__(16) unsigned short s_P[264 * PAD];  // residual [row][c], in-place
    __shared__ __align__(16) unsigned short s_Z[256 * PAD];  // z / tail staging

    const int tid  = threadIdx.x;
    const int b    = blockIdx.x >> 7;
    const int t0   = (blockIdx.x & 127) * 128;
    const int lane = tid & 63;
    const int wv   = tid >> 6;          // 0..7
    const int col  = lane & 15;
    const int quad = lane >> 4;
    const int pair = wv & 3;            // GEMM1 gate pair
    const int par  = wv >> 2;           // col-tile parity
    const int chA  = 16 * pair + 4 * quad;          // a-channel base (GEMM1)
    const int srm  = (wv < 4) ? wv : (wv - 4);      // GEMM2 ch-tile
    const int chS  = 16 * srm + 4 * quad;           // skip/res channel base
    const bool firstStack = (flags & 1) != 0;
    const bool lastStack  = (flags & 2) != 0;

    // output-tile start (tile units) per layer
    const int ts_out[6] = {0, 0, 1, 2, 4, 8};

    // zero margin rows 0..7
    for (int i = tid; i < 8 * (PAD / 2); i += 512) {
        int r = i / (PAD / 2), dw = i - r * (PAD / 2);
        ((unsigned int*)(s_P + r * PAD))[dw] = 0u;
    }
    // stage residual rows 8..263 <- abs cols [t0-128, t0+128)
    if (firstStack) {
        for (int i = tid; i < 256 * 8; i += 512) {
            int r = i >> 3, seg = i & 7;
            int g = t0 - 128 + r;
            bf16x8 v = {0, 0, 0, 0, 0, 0, 0, 0};
            if (g >= 0) {
                int xs = (g == 0) ? 0 : x[b * T_LEN + g - 1];
                const float* p = firstWT + xs * 64 + seg * 8;
                f32x4 a0 = *(const f32x4*)p;
                f32x4 a1 = *(const f32x4*)(p + 4);
                v[0] = (short)f2bf(a0[0]); v[1] = (short)f2bf(a0[1]);
                v[2] = (short)f2bf(a0[2]); v[3] = (short)f2bf(a0[3]);
                v[4] = (short)f2bf(a1[0]); v[5] = (short)f2bf(a1[1]);
                v[6] = (short)f2bf(a1[2]); v[7] = (short)f2bf(a1[3]);
            }
            *(bf16x8*)(s_P + (8 + r) * PAD + seg * 8) = v;
        }
    } else {
        const unsigned short* hb = prevH + (size_t)b * T_LEN * 64;
        for (int i = tid; i < 256 * 8; i += 512) {
            int r = i >> 3, seg = i & 7;
            int g = t0 - 128 + r;
            bf16x8 v = {0, 0, 0, 0, 0, 0, 0, 0};
            if (g >= 0) v = *(const bf16x8*)(hb + (size_t)g * 64 + seg * 8);
            *(bf16x8*)(s_P + (8 + r) * PAD + seg * 8) = v;
        }
    }

    // per-wave persistent state
    f32x4 resReg[8];    // res waves (wv>=4): fp32 residual, owned tiles
    f32x4 skipAcc[8];   // skip waves (wv<4): skip accumulator, owned tiles
#pragma unroll
    for (int i = 0; i < 8; ++i) skipAcc[i] = (f32x4){0.f, 0.f, 0.f, 0.f};
    if (wv >= 4) {
        if (firstStack) {
#pragma unroll
            for (int i = 0; i < 8; ++i) {
                int t = t0 + i * 16 + col;
                int xs = (t == 0) ? 0 : x[b * T_LEN + t - 1];
                resReg[i] = *(const f32x4*)(firstWT + xs * 64 + chS);
            }
        } else {
#pragma unroll
            for (int i = 0; i < 8; ++i)
                resReg[i] = *(const f32x4*)(prevF +
                              ((size_t)b * T_LEN + t0 + i * 16 + col) * 64 + chS);
        }
    }
    __syncthreads();

#pragma unroll 1
    for (int l = 0; l < 6; ++l) {
        const int d  = 1 << l;
        const int ts = ts_out[l];

        // GEMM1 A-fragments for this wave's gate pair
        const unsigned short* AL = ATb + (size_t)l * 128 * 288;
        bf16x8 frA0[9], frA1[9];
#pragma unroll
        for (int ks = 0; ks < 9; ++ks) {
            frA0[ks] = *(const bf16x8*)(AL + (size_t)(16 * pair + col) * 288 + ks * 32 + quad * 8);
            frA1[ks] = *(const bf16x8*)(AL + (size_t)(64 + 16 * pair + col) * 288 + ks * 32 + quad * 8);
        }
        f32x4 cbA = *(const f32x4*)(convB + l * 128 + chA);
        f32x4 cbG = *(const f32x4*)(convB + l * 128 + 64 + chA);

        // ---- GEMM1 + gated activation (tiles of this wave's parity) ----
#pragma unroll
        for (int i8 = 0; i8 < 8; ++i8) {
            const int tl = 2 * i8 + par;
            if (tl < ts) continue;
            const int r_base = 8 + tl * 16 + col;
            int g = t0 - 128 + tl * 16 + col;
            int gcl = g < 0 ? 0 : g;
            const unsigned short* fc = ffb + ((size_t)b * T_LEN + gcl) * 96 + quad * 8;
            bf16x8 f6 = *(const bf16x8*)(fc);
            bf16x8 f7 = *(const bf16x8*)(fc + 32);
            bf16x8 f8 = *(const bf16x8*)(fc + 64);
            f32x4 a0 = (f32x4){0.f, 0.f, 0.f, 0.f};
            f32x4 a1 = (f32x4){0.f, 0.f, 0.f, 0.f};
#pragma unroll
            for (int ks = 0; ks < 6; ++ks) {
                int r_in = r_base - 2 * d + (ks >> 1) * d;
                bf16x8 fB = *(const bf16x8*)(s_P + r_in * PAD + (ks & 1) * 32 + quad * 8);
                a0 = __builtin_amdgcn_mfma_f32_16x16x32_bf16(frA0[ks], fB, a0, 0, 0, 0);
                a1 = __builtin_amdgcn_mfma_f32_16x16x32_bf16(frA1[ks], fB, a1, 0, 0, 0);
            }
            a0 = __builtin_amdgcn_mfma_f32_16x16x32_bf16(frA0[6], f6, a0, 0, 0, 0);
            a1 = __builtin_amdgcn_mfma_f32_16x16x32_bf16(frA1[6], f6, a1, 0, 0, 0);
            a0 = __builtin_amdgcn_mfma_f32_16x16x32_bf16(frA0[7], f7, a0, 0, 0, 0);
            a1 = __builtin_amdgcn_mfma_f32_16x16x32_bf16(frA1[7], f7, a1, 0, 0, 0);
            a0 = __builtin_amdgcn_mfma_f32_16x16x32_bf16(frA0[8], f8, a0, 0, 0, 0);
            a1 = __builtin_amdgcn_mfma_f32_16x16x32_bf16(frA1[8], f8, a1, 0, 0, 0);

            unsigned int pk[2];
#pragma unroll
            for (int r2 = 0; r2 < 2; ++r2) {
                float zz[2];
#pragma unroll
                for (int e = 0; e < 2; ++e) {
                    float av = a0[2 * r2 + e] + cbA[2 * r2 + e];
                    float gv = a1[2 * r2 + e] + cbG[2 * r2 + e];
                    float th = 1.f - 2.f * __builtin_amdgcn_rcpf(__expf(2.f * av) + 1.f);
                    float sg = __builtin_amdgcn_rcpf(1.f + __expf(-gv));
                    zz[e] = th * sg;
                }
                pk[r2] = (unsigned int)f2bf(zz[0]) | ((unsigned int)f2bf(zz[1]) << 16);
            }
            unsigned int* zp = (unsigned int*)(s_Z + (tl * 16 + col) * PAD + chA);
            zp[0] = pk[0];
            zp[1] = pk[1];
        }
        __syncthreads();

        // ---- GEMM2 (rebalanced): skip waves = owned skip + halo res;
        //      res waves = owned res (resReg, in-place write) ----
        const unsigned short* SL = SRTb + (size_t)l * 128 * 64;
        if (wv < 4) {
            bf16x8 wk0 = *(const bf16x8*)(SL + (size_t)(16 * srm + col) * 64 + quad * 8);
            bf16x8 wk1 = *(const bf16x8*)(SL + (size_t)(16 * srm + col) * 64 + 32 + quad * 8);
            bf16x8 wr0 = *(const bf16x8*)(SL + (size_t)(64 + 16 * srm + col) * 64 + quad * 8);
            bf16x8 wr1 = *(const bf16x8*)(SL + (size_t)(64 + 16 * srm + col) * 64 + 32 + quad * 8);
            f32x4 sb4 = *(const f32x4*)(skipB + l * 64 + chS);
            f32x4 rb4 = *(const f32x4*)(resB + l * 64 + chS);
            // owned skip
#pragma unroll
            for (int i = 0; i < 8; ++i) {
                const int zr = ((8 + i) * 16 + col) * PAD;
                bf16x8 fz0 = *(const bf16x8*)(s_Z + zr + quad * 8);
                bf16x8 fz1 = *(const bf16x8*)(s_Z + zr + 32 + quad * 8);
                f32x4 s = (f32x4){0.f, 0.f, 0.f, 0.f};
                s = __builtin_amdgcn_mfma_f32_16x16x32_bf16(wk0, fz0, s, 0, 0, 0);
                s = __builtin_amdgcn_mfma_f32_16x16x32_bf16(wk1, fz1, s, 0, 0, 0);
#pragma unroll
                for (int e = 0; e < 4; ++e) skipAcc[i][e] += s[e] + sb4[e];
            }
            // halo res (in-place RMW of s_P)
#pragma unroll
            for (int tl = 0; tl < 8; ++tl) {
                if (tl < ts) continue;
                const int zr = (tl * 16 + col) * PAD;
                bf16x8 fz0 = *(const bf16x8*)(s_Z + zr + quad * 8);
                bf16x8 fz1 = *(const bf16x8*)(s_Z + zr + 32 + quad * 8);
                const int row = 8 + tl * 16 + col;
                unsigned int* pv = (unsigned int*)(s_P + row * PAD + chS);
                unsigned int w0 = pv[0], w1 = pv[1];
                f32x4 acc;
                acc[0] = __uint_as_float(w0 << 16);
                acc[1] = __uint_as_float(w0 & 0xFFFF0000u);
                acc[2] = __uint_as_float(w1 << 16);
                acc[3] = __uint_as_float(w1 & 0xFFFF0000u);
                acc = __builtin_amdgcn_mfma_f32_16x16x32_bf16(wr0, fz0, acc, 0, 0, 0);
                acc = __builtin_amdgcn_mfma_f32_16x16x32_bf16(wr1, fz1, acc, 0, 0, 0);
#pragma unroll
                for (int e = 0; e < 4; ++e) acc[e] += rb4[e];
                int g = t0 - 128 + tl * 16 + col;
                if (g < 0) acc = (f32x4){0.f, 0.f, 0.f, 0.f};
                pv[0] = (unsigned int)f2bf(acc[0]) | ((unsigned int)f2bf(acc[1]) << 16);
                pv[1] = (unsigned int)f2bf(acc[2]) | ((unsigned int)f2bf(acc[3]) << 16);
            }
        } else {
            if (!(lastStack && l == 5)) {
                bf16x8 wr0 = *(const bf16x8*)(SL + (size_t)(64 + 16 * srm + col) * 64 + quad * 8);
                bf16x8 wr1 = *(const bf16x8*)(SL + (size_t)(64 + 16 * srm + col) * 64 + 32 + quad * 8);
                f32x4 rb4 = *(const f32x4*)(resB + l * 64 + chS);
#pragma unroll
                for (int i = 0; i < 8; ++i) {
                    const int zr = ((8 + i) * 16 + col) * PAD;
                    bf16x8 fz0 = *(const bf16x8*)(s_Z + zr + quad * 8);
                    bf16x8 fz1 = *(const bf16x8*)(s_Z + zr + 32 + quad * 8);
                    f32x4 acc = resReg[i];
                    acc = __builtin_amdgcn_mfma_f32_16x16x32_bf16(wr0, fz0, acc, 0, 0, 0);
                    acc = __builtin_amdgcn_mfma_f32_16x16x32_bf16(wr1, fz1, acc, 0, 0, 0);
#pragma unroll
                    for (int e = 0; e < 4; ++e) acc[e] += rb4[e];
                    resReg[i] = acc;
                    if (l < 5) {
                        const int row = 8 + (8 + i) * 16 + col;
                        unsigned int* qp = (unsigned int*)(s_P + row * PAD + chS);
                        qp[0] = (unsigned int)f2bf(acc[0]) | ((unsigned int)f2bf(acc[1]) << 16);
                        qp[1] = (unsigned int)f2bf(acc[2]) | ((unsigned int)f2bf(acc[3]) << 16);
                    }
                }
            }
        }
        __syncthreads();
    }

    // ---------------- epilogue ----------------
    if (!lastStack) {
        if (wv >= 4) {
#pragma unroll
            for (int i = 0; i < 8; ++i) {
                size_t base = ((size_t)b * T_LEN + t0 + i * 16 + col) * 64 + chS;
                *(f32x4*)(nextF + base) = resReg[i];
                unsigned int p01 = (unsigned int)f2bf(resReg[i][0]) | ((unsigned int)f2bf(resReg[i][1]) << 16);
                unsigned int p23 = (unsigned int)f2bf(resReg[i][2]) | ((unsigned int)f2bf(resReg[i][3]) << 16);
                unsigned int* hp = (unsigned int*)(nextH + base);
                hp[0] = p01;
                hp[1] = p23;
            }
        } else {
#pragma unroll
            for (int i = 0; i < 8; ++i) {
                size_t base = ((size_t)b * T_LEN + t0 + i * 16 + col) * 64 + chS;
                if (firstStack) {
                    *(f32x4*)(skipF + base) = skipAcc[i];
                } else {
                    f32x4 s = *(const f32x4*)(skipF + base);
#pragma unroll
                    for (int e = 0; e < 4; ++e) s[e] += skipAcc[i][e];
                    *(f32x4*)(skipF + base) = s;
                }
            }
        }
        return;
    }

    // ---------------- fused tail (last stack) ----------------
    unsigned short* s_S = s_Z;
    unsigned short* s_H = s_Z + 128 * PAD;
    if (wv < 4) {
#pragma unroll
        for (int i = 0; i < 8; ++i) {
            size_t base = ((size_t)b * T_LEN + t0 + i * 16 + col) * 64 + chS;
            f32x4 s = *(const f32x4*)(skipF + base);
            float v0 = fmaxf(s[0] + skipAcc[i][0], 0.f);
            float v1 = fmaxf(s[1] + skipAcc[i][1], 0.f);
            float v2 = fmaxf(s[2] + skipAcc[i][2], 0.f);
            float v3 = fmaxf(s[3] + skipAcc[i][3], 0.f);
            unsigned int* sp = (unsigned int*)(s_S + (i * 16 + col) * PAD + chS);
            sp[0] = (unsigned int)f2bf(v0) | ((unsigned int)f2bf(v1) << 16);
            sp[1] = (unsigned int)f2bf(v2) | ((unsigned int)f2bf(v3) << 16);
        }
    }
    __syncthreads();

    // last1: h2 = relu(W1 @ relu(skip) + b1)
    {
        const int m1 = wv & 3;
        const int q1 = wv >> 2;
        bf16x8 fw0 = *(const bf16x8*)(W1b + (size_t)(16 * m1 + col) * 64 + quad * 8);
        bf16x8 fw1 = *(const bf16x8*)(W1b + (size_t)(16 * m1 + col) * 64 + 32 + quad * 8);
        f32x4 bb1 = *(const f32x4*)(b1 + 16 * m1 + 4 * quad);
#pragma unroll
        for (int i = 0; i < 8; ++i) {
            if ((i & 1) != q1) continue;
            const int zr = (i * 16 + col) * PAD;
            bf16x8 fz0 = *(const bf16x8*)(s_S + zr + quad * 8);
            bf16x8 fz1 = *(const bf16x8*)(s_S + zr + 32 + quad * 8);
            f32x4 a = (f32x4){0.f, 0.f, 0.f, 0.f};
            a = __builtin_amdgcn_mfma_f32_16x16x32_bf16(fw0, fz0, a, 0, 0, 0);
            a = __builtin_amdgcn_mfma_f32_16x16x32_bf16(fw1, fz1, a, 0, 0, 0);
            float h0 = fmaxf(a[0] + bb1[0], 0.f), h1 = fmaxf(a[1] + bb1[1], 0.f);
            float h2 = fmaxf(a[2] + bb1[2], 0.f), h3 = fmaxf(a[3] + bb1[3], 0.f);
            unsigned int* hp = (unsigned int*)(s_H + (i * 16 + col) * PAD + 16 * m1 + 4 * quad);
            hp[0] = (unsigned int)f2bf(h0) | ((unsigned int)f2bf(h1) << 16);
            hp[1] = (unsigned int)f2bf(h2) | ((unsigned int)f2bf(h3) << 16);
        }
    }
    __syncthreads();

    // last2: out = W2 @ h2 + b2  (fp32 c-major)
#pragma unroll
    for (int p2 = 0; p2 < 2; ++p2) {
        const int m2 = wv + 8 * p2;
        bf16x8 fw0 = *(const bf16x8*)(W2b + (size_t)(16 * m2 + col) * 64 + quad * 8);
        bf16x8 fw1 = *(const bf16x8*)(W2b + (size_t)(16 * m2 + col) * 64 + 32 + quad * 8);
        f32x4 bb2 = *(const f32x4*)(b2 + 16 * m2 + 4 * quad);
#pragma unroll
        for (int i = 0; i < 8; ++i) {
            const int zr = (i * 16 + col) * PAD;
            bf16x8 fz0 = *(const bf16x8*)(s_H + zr + quad * 8);
            bf16x8 fz1 = *(const bf16x8*)(s_H + zr + 32 + quad * 8);
            f32x4 a = (f32x4){0.f, 0.f, 0.f, 0.f};
            a = __builtin_amdgcn_mfma_f32_16x16x32_bf16(fw0, fz0, a, 0, 0, 0);
            a = __builtin_amdgcn_mfma_f32_16x16x32_bf16(fw1, fz1, a, 0, 0, 0);
            int t = t0 + i * 16 + col;
            int o0 = 16 * m2 + 4 * quad;
#pragma unroll
            for (int e = 0; e < 4; ++e)
                outp[((size_t)b * 256 + o0 + e) * T_LEN + t] = a[e] + bb2[e];
        }
    }
}

// ---------------------------------------------------------------------------
extern "C" void kernel_launch(void* const* d_in, const int* in_sizes, int n_in,
                              void* d_out, int out_size, void* d_ws, size_t ws_size,
                              hipStream_t stream) {
    const int*   x       = (const int*)  d_in[0];
    const float* feature = (const float*)d_in[1];
    const float* firstW  = (const float*)d_in[2];
    const float* firstb  = (const float*)d_in[3];
    const float* convW   = (const float*)d_in[4];
    const float* convB   = (const float*)d_in[5];
    const float* condW   = (const float*)d_in[6];
    const float* skipW   = (const float*)d_in[7];
    const float* skipB   = (const float*)d_in[8];
    const float* resW    = (const float*)d_in[9];
    const float* resB    = (const float*)d_in[10];
    const float* last1W  = (const float*)d_in[11];
    const float* last1b  = (const float*)d_in[12];
    const float* last2W  = (const float*)d_in[13];
    const float* last2b  = (const float*)d_in[14];
    const float* convinW = (const float*)d_in[15];
    const float* upK     = (const float*)d_in[16];

    float* ws = (float*)d_ws;
    float* f0      = ws;                       // 10240
    float* f1      = f0 + 10240;               // 40960
    float* f2      = f1 + 40960;               // 163840
    float* f3      = f2 + 163840;              // 655360
    float* firstWT = f3 + 655360;              // 16384
    float* resA    = firstWT + 16384;          // 2097152
    float* resB_   = resA + 2097152;           // 2097152
    float* skipF   = resB_ + 2097152;          // 2097152
    unsigned short* mirA = (unsigned short*)(skipF + 2097152);  // 2097152
    unsigned short* mirB = mirA + 2097152;                      // 2097152
    unsigned short* ffb  = mirB + 2097152;                      // 3145728
    unsigned short* ATb  = ffb + 3145728;                       // 884736
    unsigned short* SRTb = ATb + 884736;                        // 196608
    unsigned short* W1b  = SRTb + 196608;                       // 4096
    unsigned short* W2b  = W1b + 4096;                          // 16384

    int n;
    n = NLAYERS * 128 * 288 + NLAYERS * 128 * 64 + 4096 + 16384 + 16384;
    k_pack<<<(n + 255) / 256, 256, 0, stream>>>(convW, condW, skipW, resW, last1W, last2W,
                                                firstW, firstb, ATb, SRTb, W1b, W2b, firstWT);
    n = NB * FCH * 64;
    k_convin<<<(n + 255) / 256, 256, 0, stream>>>(feature, convinW, f0);
    k_up<<<(NB * FCH * 256 + 255) / 256, 256, 0, stream>>>(f0, f1, upK + 0, 64);
    k_up<<<(NB * FCH * 1024 + 255) / 256, 256, 0, stream>>>(f1, f2, upK + 9, 256);
    k_up<<<(NB * FCH * 4096 + 255) / 256, 256, 0, stream>>>(f2, f3, upK + 18, 1024);
    k_up_last<<<NB * 256, 256, 0, stream>>>(f3, ffb, upK + 27);

    float* poF = resA;          float* pnF = resB_;
    unsigned short* poH = mirA; unsigned short* pnH = mirB;
    for (int s = 0; s < 4; ++s) {
        int flags = (s == 0 ? 1 : 0) | (s == 3 ? 2 : 0);
        k_stack<<<NB * 128, 512, 0, stream>>>(
            x, firstWT, poF, poH, pnF, pnH, skipF, ffb,
            ATb + (size_t)s * 6 * 128 * 288, SRTb + (size_t)s * 6 * 128 * 64,
            convB + s * 6 * 128, skipB + s * 6 * 64, resB + s * 6 * 64,
            W1b, last1b, W2b, last2b, (float*)d_out, flags);
        float* tf = poF; poF = pnF; pnF = tf;
        unsigned short* th = poH; poH = pnH; pnH = th;
    }
}

// Round 10
// 399.495 us; speedup vs baseline: 1.9799x; 1.9799x over previous
//
#include <hip/hip_runtime.h>
#include <math.h>

#define T_LEN   16384
#define NB      2
#define FCH     80
#define NLAYERS 24
#define TFRAMES 68
#define PAD     76

typedef __attribute__((ext_vector_type(8))) short bf16x8;
typedef __attribute__((ext_vector_type(4))) float f32x4;

static __device__ inline unsigned short f2bf(float f) {
    unsigned int u = __float_as_uint(f);
    unsigned int r = (u + 0x7FFFu + ((u >> 16) & 1u)) >> 16;
    return (unsigned short)r;
}

// ---------------------------------------------------------------------------
// Pack: bf16 weight layouts + firstWT (transposed embedding table, bias folded)
// ---------------------------------------------------------------------------
__global__ void k_pack(const float* __restrict__ convW, const float* __restrict__ condW,
                       const float* __restrict__ skipW, const float* __restrict__ resW,
                       const float* __restrict__ last1W, const float* __restrict__ last2W,
                       const float* __restrict__ firstW, const float* __restrict__ firstb,
                       unsigned short* __restrict__ ATb, unsigned short* __restrict__ SRTb,
                       unsigned short* __restrict__ W1b, unsigned short* __restrict__ W2b,
                       float* __restrict__ firstWT) {
    int idx = blockIdx.x * 256 + threadIdx.x;
    const int nAT = NLAYERS * 128 * 288;
    const int nSR = NLAYERS * 128 * 64;
    const int e0 = nAT, e1 = e0 + nSR, e2 = e1 + 4096, e3 = e2 + 16384, e4 = e3 + 16384;
    if (idx < e0) {
        int k = idx % 288;
        int o = (idx / 288) & 127;
        int l = idx / (288 * 128);
        float v = 0.f;
        if (k < 192) v = convW[(((l * 128 + o) * 64) + (k & 63)) * 3 + (k >> 6)];
        else if (k - 192 < 80) v = condW[(l * 128 + o) * 80 + (k - 192)];
        ATb[idx] = f2bf(v);
    } else if (idx < e1) {
        int j = idx - e0;
        int k = j & 63;
        int o2 = (j >> 6) & 127;
        int l = j / (64 * 128);
        float v = (o2 < 64) ? skipW[(l * 64 + o2) * 64 + k]
                            : resW[(l * 64 + (o2 - 64)) * 64 + k];
        SRTb[j] = f2bf(v);
    } else if (idx < e2) {
        W1b[idx - e1] = f2bf(last1W[idx - e1]);
    } else if (idx < e3) {
        W2b[idx - e2] = f2bf(last2W[idx - e2]);
    } else if (idx < e4) {
        int j = idx - e3;
        int xs = j >> 6, c = j & 63;
        firstWT[j] = firstW[c * 256 + xs] + firstb[c];
    }
}

// ---------------------------------------------------------------------------
// ConvIn: valid conv, kernel 5, (B,80,68) -> (B,80,64)
// ---------------------------------------------------------------------------
__global__ void k_convin(const float* __restrict__ feat, const float* __restrict__ W,
                         float* __restrict__ f0) {
    int idx = blockIdx.x * 256 + threadIdx.x;
    if (idx >= NB * FCH * 64) return;
    int t = idx & 63;
    int o = (idx >> 6) % FCH;
    int b = idx / (64 * FCH);
    const float* fb = feat + b * FCH * TFRAMES;
    const float* wo = W + o * FCH * 5;
    float acc = 0.f;
    for (int i = 0; i < FCH; ++i) {
        const float* fi = fb + i * TFRAMES + t;
        const float* wi = wo + i * 5;
#pragma unroll
        for (int k = 0; k < 5; ++k) acc += fi[k] * wi[k];
    }
    f0[idx] = acc;
}

// ---------------------------------------------------------------------------
// Upsample stage (x4 repeat + 9-tap smooth), fp32 c-major
// ---------------------------------------------------------------------------
__global__ void k_up(const float* __restrict__ in, float* __restrict__ out,
                     const float* __restrict__ kern, int Tin) {
    int Tout = Tin * 4;
    int idx = blockIdx.x * 256 + threadIdx.x;
    if (idx >= NB * FCH * Tout) return;
    int t = idx % Tout;
    int bc = idx / Tout;
    const float* ib = in + bc * Tin;
    float acc = 0.f;
#pragma unroll
    for (int k = 0; k < 9; ++k) {
        int u = t + k - 4;
        if (u >= 0 && u < Tout) acc += kern[k] * ib[u >> 2];
    }
    out[idx] = acc;
}

// ---------------------------------------------------------------------------
// Last upsample -> bf16 TIME-MAJOR [b][t][96], LDS-staged source frames
// ---------------------------------------------------------------------------
__global__ __launch_bounds__(256)
void k_up_last(const float* __restrict__ in, unsigned short* __restrict__ outH,
               const float* __restrict__ kern) {
    __shared__ float sF[18 * 80];
    const int tid = threadIdx.x;
    const int b  = blockIdx.x >> 8;
    const int t0 = (blockIdx.x & 255) * 64;
    const int fr0 = (t0 >> 2) - 1;

    for (int idx = tid; idx < 18 * 80; idx += 256) {
        int c = idx / 18, fr = idx - c * 18;
        int gfr = fr0 + fr;
        float v = 0.f;
        if (gfr >= 0 && gfr < 4096) v = in[((size_t)b * 80 + c) * 4096 + gfr];
        sF[fr * 80 + c] = v;
    }
    float kr[9];
#pragma unroll
    for (int k = 0; k < 9; ++k) kr[k] = kern[k];
    __syncthreads();

    for (int idx = tid; idx < 64 * 96; idx += 256) {
        int c = idx % 96;
        int t = idx / 96;
        float acc = 0.f;
        if (c < 80) {
            int ubase = t0 + t - 4;
#pragma unroll
            for (int k = 0; k < 9; ++k) {
                int fr = ((ubase + k) >> 2) - fr0;
                acc += kr[k] * sF[fr * 80 + c];
            }
        }
        outH[((size_t)b * T_LEN + t0 + t) * 96 + c] = f2bf(acc);
    }
}

// ---------------------------------------------------------------------------
// STACK KERNEL v3.1: single LDS residual buffer (in-place GEMM2), 79 KB LDS,
// PAD=76, R8 work assignment (skip waves: skip only; res waves: halo+owned),
// __launch_bounds__(512,1) — R8's proven 104-VGPR budget (R9's (512,4) spilled).
// flags: bit0 = first stack, bit1 = last stack
// ---------------------------------------------------------------------------
__global__ __launch_bounds__(512, 1)
void k_stack(const int* __restrict__ x, const float* __restrict__ firstWT,
             const float* __restrict__ prevF, const unsigned short* __restrict__ prevH,
             float* __restrict__ nextF, unsigned short* __restrict__ nextH,
             float* __restrict__ skipF, const unsigned short* __restrict__ ffb,
             const unsigned short* __restrict__ ATb, const unsigned short* __restrict__ SRTb,
             const float* __restrict__ convB, const float* __restrict__ skipB,
             const float* __restrict__ resB,
             const unsigned short* __restrict__ W1b, const float* __restrict__ b1,
             const unsigned short* __restrict__ W2b, const float* __restrict__ b2,
             float* __restrict__ outp, int flags)
{
    __shared__ __align__(16) unsigned short s_P[264 * PAD];  // residual [row][c], in-place
    __shared__ __align__(16) unsigned short s_Z[256 * PAD];  // z / tail staging

    const int tid  = threadIdx.x;
    const int b    = blockIdx.x >> 7;
    const int t0   = (blockIdx.x & 127) * 128;
    const int lane = tid & 63;
    const int wv   = tid >> 6;          // 0..7
    const int col  = lane & 15;
    const int quad = lane >> 4;
    const int pair = wv & 3;            // GEMM1 gate pair
    const int par  = wv >> 2;           // col-tile parity
    const int chA  = 16 * pair + 4 * quad;          // a-channel base (GEMM1)
    const int srm  = (wv < 4) ? wv : (wv - 4);      // GEMM2 ch-tile
    const int chS  = 16 * srm + 4 * quad;           // skip/res channel base
    const bool firstStack = (flags & 1) != 0;
    const bool lastStack  = (flags & 2) != 0;

    // output-tile start (tile units) per layer
    const int ts_out[6] = {0, 0, 1, 2, 4, 8};

    // zero margin rows 0..7
    for (int i = tid; i < 8 * (PAD / 2); i += 512) {
        int r = i / (PAD / 2), dw = i - r * (PAD / 2);
        ((unsigned int*)(s_P + r * PAD))[dw] = 0u;
    }
    // stage residual rows 8..263 <- abs cols [t0-128, t0+128)
    if (firstStack) {
        for (int i = tid; i < 256 * 8; i += 512) {
            int r = i >> 3, seg = i & 7;
            int g = t0 - 128 + r;
            bf16x8 v = {0, 0, 0, 0, 0, 0, 0, 0};
            if (g >= 0) {
                int xs = (g == 0) ? 0 : x[b * T_LEN + g - 1];
                const float* p = firstWT + xs * 64 + seg * 8;
                f32x4 a0 = *(const f32x4*)p;
                f32x4 a1 = *(const f32x4*)(p + 4);
                v[0] = (short)f2bf(a0[0]); v[1] = (short)f2bf(a0[1]);
                v[2] = (short)f2bf(a0[2]); v[3] = (short)f2bf(a0[3]);
                v[4] = (short)f2bf(a1[0]); v[5] = (short)f2bf(a1[1]);
                v[6] = (short)f2bf(a1[2]); v[7] = (short)f2bf(a1[3]);
            }
            *(bf16x8*)(s_P + (8 + r) * PAD + seg * 8) = v;
        }
    } else {
        const unsigned short* hb = prevH + (size_t)b * T_LEN * 64;
        for (int i = tid; i < 256 * 8; i += 512) {
            int r = i >> 3, seg = i & 7;
            int g = t0 - 128 + r;
            bf16x8 v = {0, 0, 0, 0, 0, 0, 0, 0};
            if (g >= 0) v = *(const bf16x8*)(hb + (size_t)g * 64 + seg * 8);
            *(bf16x8*)(s_P + (8 + r) * PAD + seg * 8) = v;
        }
    }

    // per-wave persistent state
    f32x4 resReg[8];    // res waves (wv>=4): fp32 residual, owned tiles
    f32x4 skipAcc[8];   // skip waves (wv<4): skip accumulator, owned tiles
#pragma unroll
    for (int i = 0; i < 8; ++i) skipAcc[i] = (f32x4){0.f, 0.f, 0.f, 0.f};
    if (wv >= 4) {
        if (firstStack) {
#pragma unroll
            for (int i = 0; i < 8; ++i) {
                int t = t0 + i * 16 + col;
                int xs = (t == 0) ? 0 : x[b * T_LEN + t - 1];
                resReg[i] = *(const f32x4*)(firstWT + xs * 64 + chS);
            }
        } else {
#pragma unroll
            for (int i = 0; i < 8; ++i)
                resReg[i] = *(const f32x4*)(prevF +
                              ((size_t)b * T_LEN + t0 + i * 16 + col) * 64 + chS);
        }
    }
    __syncthreads();

#pragma unroll 1
    for (int l = 0; l < 6; ++l) {
        const int d  = 1 << l;
        const int ts = ts_out[l];

        // GEMM1 A-fragments for this wave's gate pair
        const unsigned short* AL = ATb + (size_t)l * 128 * 288;
        bf16x8 frA0[9], frA1[9];
#pragma unroll
        for (int ks = 0; ks < 9; ++ks) {
            frA0[ks] = *(const bf16x8*)(AL + (size_t)(16 * pair + col) * 288 + ks * 32 + quad * 8);
            frA1[ks] = *(const bf16x8*)(AL + (size_t)(64 + 16 * pair + col) * 288 + ks * 32 + quad * 8);
        }
        f32x4 cbA = *(const f32x4*)(convB + l * 128 + chA);
        f32x4 cbG = *(const f32x4*)(convB + l * 128 + 64 + chA);

        // ---- GEMM1 + gated activation (tiles of this wave's parity) ----
#pragma unroll 1
        for (int tl = ts; tl < 16; ++tl) {
            if ((tl & 1) != par) continue;
            const int r_base = 8 + tl * 16 + col;
            int g = t0 - 128 + tl * 16 + col;
            int gcl = g < 0 ? 0 : g;
            const unsigned short* fc = ffb + ((size_t)b * T_LEN + gcl) * 96 + quad * 8;
            bf16x8 f6 = *(const bf16x8*)(fc);
            bf16x8 f7 = *(const bf16x8*)(fc + 32);
            bf16x8 f8 = *(const bf16x8*)(fc + 64);
            f32x4 a0 = (f32x4){0.f, 0.f, 0.f, 0.f};
            f32x4 a1 = (f32x4){0.f, 0.f, 0.f, 0.f};
#pragma unroll
            for (int ks = 0; ks < 6; ++ks) {
                int r_in = r_base - 2 * d + (ks >> 1) * d;
                bf16x8 fB = *(const bf16x8*)(s_P + r_in * PAD + (ks & 1) * 32 + quad * 8);
                a0 = __builtin_amdgcn_mfma_f32_16x16x32_bf16(frA0[ks], fB, a0, 0, 0, 0);
                a1 = __builtin_amdgcn_mfma_f32_16x16x32_bf16(frA1[ks], fB, a1, 0, 0, 0);
            }
            a0 = __builtin_amdgcn_mfma_f32_16x16x32_bf16(frA0[6], f6, a0, 0, 0, 0);
            a1 = __builtin_amdgcn_mfma_f32_16x16x32_bf16(frA1[6], f6, a1, 0, 0, 0);
            a0 = __builtin_amdgcn_mfma_f32_16x16x32_bf16(frA0[7], f7, a0, 0, 0, 0);
            a1 = __builtin_amdgcn_mfma_f32_16x16x32_bf16(frA1[7], f7, a1, 0, 0, 0);
            a0 = __builtin_amdgcn_mfma_f32_16x16x32_bf16(frA0[8], f8, a0, 0, 0, 0);
            a1 = __builtin_amdgcn_mfma_f32_16x16x32_bf16(frA1[8], f8, a1, 0, 0, 0);

            unsigned int pk[2];
#pragma unroll
            for (int r2 = 0; r2 < 2; ++r2) {
                float zz[2];
#pragma unroll
                for (int e = 0; e < 2; ++e) {
                    float av = a0[2 * r2 + e] + cbA[2 * r2 + e];
                    float gv = a1[2 * r2 + e] + cbG[2 * r2 + e];
                    float th = 1.f - 2.f * __builtin_amdgcn_rcpf(__expf(2.f * av) + 1.f);
                    float sg = __builtin_amdgcn_rcpf(1.f + __expf(-gv));
                    zz[e] = th * sg;
                }
                pk[r2] = (unsigned int)f2bf(zz[0]) | ((unsigned int)f2bf(zz[1]) << 16);
            }
            unsigned int* zp = (unsigned int*)(s_Z + (tl * 16 + col) * PAD + chA);
            zp[0] = pk[0];
            zp[1] = pk[1];
        }
        __syncthreads();

        // ---- GEMM2 (R8 assignment): skip waves = owned skip;
        //      res waves = halo res (in-place RMW) + owned res (resReg) ----
        const unsigned short* SL = SRTb + (size_t)l * 128 * 64;
        if (wv < 4) {
            bf16x8 wk0 = *(const bf16x8*)(SL + (size_t)(16 * srm + col) * 64 + quad * 8);
            bf16x8 wk1 = *(const bf16x8*)(SL + (size_t)(16 * srm + col) * 64 + 32 + quad * 8);
            f32x4 sb4 = *(const f32x4*)(skipB + l * 64 + chS);
#pragma unroll
            for (int i = 0; i < 8; ++i) {
                const int zr = ((8 + i) * 16 + col) * PAD;
                bf16x8 fz0 = *(const bf16x8*)(s_Z + zr + quad * 8);
                bf16x8 fz1 = *(const bf16x8*)(s_Z + zr + 32 + quad * 8);
                f32x4 s = (f32x4){0.f, 0.f, 0.f, 0.f};
                s = __builtin_amdgcn_mfma_f32_16x16x32_bf16(wk0, fz0, s, 0, 0, 0);
                s = __builtin_amdgcn_mfma_f32_16x16x32_bf16(wk1, fz1, s, 0, 0, 0);
#pragma unroll
                for (int e = 0; e < 4; ++e) skipAcc[i][e] += s[e] + sb4[e];
            }
        } else {
            bf16x8 wr0 = *(const bf16x8*)(SL + (size_t)(64 + 16 * srm + col) * 64 + quad * 8);
            bf16x8 wr1 = *(const bf16x8*)(SL + (size_t)(64 + 16 * srm + col) * 64 + 32 + quad * 8);
            f32x4 rb4 = *(const f32x4*)(resB + l * 64 + chS);
            // halo tiles: in-place RMW of s_P
#pragma unroll 1
            for (int tl = ts; tl < 8; ++tl) {
                const int zr = (tl * 16 + col) * PAD;
                bf16x8 fz0 = *(const bf16x8*)(s_Z + zr + quad * 8);
                bf16x8 fz1 = *(const bf16x8*)(s_Z + zr + 32 + quad * 8);
                const int row = 8 + tl * 16 + col;
                unsigned int* pv = (unsigned int*)(s_P + row * PAD + chS);
                unsigned int w0 = pv[0], w1 = pv[1];
                f32x4 acc;
                acc[0] = __uint_as_float(w0 << 16);
                acc[1] = __uint_as_float(w0 & 0xFFFF0000u);
                acc[2] = __uint_as_float(w1 << 16);
                acc[3] = __uint_as_float(w1 & 0xFFFF0000u);
                acc = __builtin_amdgcn_mfma_f32_16x16x32_bf16(wr0, fz0, acc, 0, 0, 0);
                acc = __builtin_amdgcn_mfma_f32_16x16x32_bf16(wr1, fz1, acc, 0, 0, 0);
#pragma unroll
                for (int e = 0; e < 4; ++e) acc[e] += rb4[e];
                int g = t0 - 128 + tl * 16 + col;
                if (g < 0) acc = (f32x4){0.f, 0.f, 0.f, 0.f};
                pv[0] = (unsigned int)f2bf(acc[0]) | ((unsigned int)f2bf(acc[1]) << 16);
                pv[1] = (unsigned int)f2bf(acc[2]) | ((unsigned int)f2bf(acc[3]) << 16);
            }
            // owned tiles
            if (!(lastStack && l == 5)) {
#pragma unroll
                for (int i = 0; i < 8; ++i) {
                    const int zr = ((8 + i) * 16 + col) * PAD;
                    bf16x8 fz0 = *(const bf16x8*)(s_Z + zr + quad * 8);
                    bf16x8 fz1 = *(const bf16x8*)(s_Z + zr + 32 + quad * 8);
                    f32x4 acc = resReg[i];
                    acc = __builtin_amdgcn_mfma_f32_16x16x32_bf16(wr0, fz0, acc, 0, 0, 0);
                    acc = __builtin_amdgcn_mfma_f32_16x16x32_bf16(wr1, fz1, acc, 0, 0, 0);
#pragma unroll
                    for (int e = 0; e < 4; ++e) acc[e] += rb4[e];
                    resReg[i] = acc;
                    if (l < 5) {
                        const int row = 8 + (8 + i) * 16 + col;
                        unsigned int* qp = (unsigned int*)(s_P + row * PAD + chS);
                        qp[0] = (unsigned int)f2bf(acc[0]) | ((unsigned int)f2bf(acc[1]) << 16);
                        qp[1] = (unsigned int)f2bf(acc[2]) | ((unsigned int)f2bf(acc[3]) << 16);
                    }
                }
            }
        }
        __syncthreads();
    }

    // ---------------- epilogue ----------------
    if (!lastStack) {
        if (wv >= 4) {
#pragma unroll
            for (int i = 0; i < 8; ++i) {
                size_t base = ((size_t)b * T_LEN + t0 + i * 16 + col) * 64 + chS;
                *(f32x4*)(nextF + base) = resReg[i];
                unsigned int p01 = (unsigned int)f2bf(resReg[i][0]) | ((unsigned int)f2bf(resReg[i][1]) << 16);
                unsigned int p23 = (unsigned int)f2bf(resReg[i][2]) | ((unsigned int)f2bf(resReg[i][3]) << 16);
                unsigned int* hp = (unsigned int*)(nextH + base);
                hp[0] = p01;
                hp[1] = p23;
            }
        } else {
#pragma unroll
            for (int i = 0; i < 8; ++i) {
                size_t base = ((size_t)b * T_LEN + t0 + i * 16 + col) * 64 + chS;
                if (firstStack) {
                    *(f32x4*)(skipF + base) = skipAcc[i];
                } else {
                    f32x4 s = *(const f32x4*)(skipF + base);
#pragma unroll
                    for (int e = 0; e < 4; ++e) s[e] += skipAcc[i][e];
                    *(f32x4*)(skipF + base) = s;
                }
            }
        }
        return;
    }

    // ---------------- fused tail (last stack) ----------------
    unsigned short* s_S = s_Z;
    unsigned short* s_H = s_Z + 128 * PAD;
    if (wv < 4) {
#pragma unroll
        for (int i = 0; i < 8; ++i) {
            size_t base = ((size_t)b * T_LEN + t0 + i * 16 + col) * 64 + chS;
            f32x4 s = *(const f32x4*)(skipF + base);
            float v0 = fmaxf(s[0] + skipAcc[i][0], 0.f);
            float v1 = fmaxf(s[1] + skipAcc[i][1], 0.f);
            float v2 = fmaxf(s[2] + skipAcc[i][2], 0.f);
            float v3 = fmaxf(s[3] + skipAcc[i][3], 0.f);
            unsigned int* sp = (unsigned int*)(s_S + (i * 16 + col) * PAD + chS);
            sp[0] = (unsigned int)f2bf(v0) | ((unsigned int)f2bf(v1) << 16);
            sp[1] = (unsigned int)f2bf(v2) | ((unsigned int)f2bf(v3) << 16);
        }
    }
    __syncthreads();

    // last1: h2 = relu(W1 @ relu(skip) + b1)
    {
        const int m1 = wv & 3;
        const int q1 = wv >> 2;
        bf16x8 fw0 = *(const bf16x8*)(W1b + (size_t)(16 * m1 + col) * 64 + quad * 8);
        bf16x8 fw1 = *(const bf16x8*)(W1b + (size_t)(16 * m1 + col) * 64 + 32 + quad * 8);
        f32x4 bb1 = *(const f32x4*)(b1 + 16 * m1 + 4 * quad);
#pragma unroll
        for (int i = 0; i < 8; ++i) {
            if ((i & 1) != q1) continue;
            const int zr = (i * 16 + col) * PAD;
            bf16x8 fz0 = *(const bf16x8*)(s_S + zr + quad * 8);
            bf16x8 fz1 = *(const bf16x8*)(s_S + zr + 32 + quad * 8);
            f32x4 a = (f32x4){0.f, 0.f, 0.f, 0.f};
            a = __builtin_amdgcn_mfma_f32_16x16x32_bf16(fw0, fz0, a, 0, 0, 0);
            a = __builtin_amdgcn_mfma_f32_16x16x32_bf16(fw1, fz1, a, 0, 0, 0);
            float h0 = fmaxf(a[0] + bb1[0], 0.f), h1 = fmaxf(a[1] + bb1[1], 0.f);
            float h2 = fmaxf(a[2] + bb1[2], 0.f), h3 = fmaxf(a[3] + bb1[3], 0.f);
            unsigned int* hp = (unsigned int*)(s_H + (i * 16 + col) * PAD + 16 * m1 + 4 * quad);
            hp[0] = (unsigned int)f2bf(h0) | ((unsigned int)f2bf(h1) << 16);
            hp[1] = (unsigned int)f2bf(h2) | ((unsigned int)f2bf(h3) << 16);
        }
    }
    __syncthreads();

    // last2: out = W2 @ h2 + b2  (fp32 c-major)
#pragma unroll
    for (int p2 = 0; p2 < 2; ++p2) {
        const int m2 = wv + 8 * p2;
        bf16x8 fw0 = *(const bf16x8*)(W2b + (size_t)(16 * m2 + col) * 64 + quad * 8);
        bf16x8 fw1 = *(const bf16x8*)(W2b + (size_t)(16 * m2 + col) * 64 + 32 + quad * 8);
        f32x4 bb2 = *(const f32x4*)(b2 + 16 * m2 + 4 * quad);
#pragma unroll
        for (int i = 0; i < 8; ++i) {
            const int zr = (i * 16 + col) * PAD;
            bf16x8 fz0 = *(const bf16x8*)(s_H + zr + quad * 8);
            bf16x8 fz1 = *(const bf16x8*)(s_H + zr + 32 + quad * 8);
            f32x4 a = (f32x4){0.f, 0.f, 0.f, 0.f};
            a = __builtin_amdgcn_mfma_f32_16x16x32_bf16(fw0, fz0, a, 0, 0, 0);
            a = __builtin_amdgcn_mfma_f32_16x16x32_bf16(fw1, fz1, a, 0, 0, 0);
            int t = t0 + i * 16 + col;
            int o0 = 16 * m2 + 4 * quad;
#pragma unroll
            for (int e = 0; e < 4; ++e)
                outp[((size_t)b * 256 + o0 + e) * T_LEN + t] = a[e] + bb2[e];
        }
    }
}

// ---------------------------------------------------------------------------
extern "C" void kernel_launch(void* const* d_in, const int* in_sizes, int n_in,
                              void* d_out, int out_size, void* d_ws, size_t ws_size,
                              hipStream_t stream) {
    const int*   x       = (const int*)  d_in[0];
    const float* feature = (const float*)d_in[1];
    const float* firstW  = (const float*)d_in[2];
    const float* firstb  = (const float*)d_in[3];
    const float* convW   = (const float*)d_in[4];
    const float* convB   = (const float*)d_in[5];
    const float* condW   = (const float*)d_in[6];
    const float* skipW   = (const float*)d_in[7];
    const float* skipB   = (const float*)d_in[8];
    const float* resW    = (const float*)d_in[9];
    const float* resB    = (const float*)d_in[10];
    const float* last1W  = (const float*)d_in[11];
    const float* last1b  = (const float*)d_in[12];
    const float* last2W  = (const float*)d_in[13];
    const float* last2b  = (const float*)d_in[14];
    const float* convinW = (const float*)d_in[15];
    const float* upK     = (const float*)d_in[16];

    float* ws = (float*)d_ws;
    float* f0      = ws;                       // 10240
    float* f1      = f0 + 10240;               // 40960
    float* f2      = f1 + 40960;               // 163840
    float* f3      = f2 + 163840;              // 655360
    float* firstWT = f3 + 655360;              // 16384
    float* resA    = firstWT + 16384;          // 2097152
    float* resB_   = resA + 2097152;           // 2097152
    float* skipF   = resB_ + 2097152;          // 2097152
    unsigned short* mirA = (unsigned short*)(skipF + 2097152);  // 2097152
    unsigned short* mirB = mirA + 2097152;                      // 2097152
    unsigned short* ffb  = mirB + 2097152;                      // 3145728
    unsigned short* ATb  = ffb + 3145728;                       // 884736
    unsigned short* SRTb = ATb + 884736;                        // 196608
    unsigned short* W1b  = SRTb + 196608;                       // 4096
    unsigned short* W2b  = W1b + 4096;                          // 16384

    int n;
    n = NLAYERS * 128 * 288 + NLAYERS * 128 * 64 + 4096 + 16384 + 16384;
    k_pack<<<(n + 255) / 256, 256, 0, stream>>>(convW, condW, skipW, resW, last1W, last2W,
                                                firstW, firstb, ATb, SRTb, W1b, W2b, firstWT);
    n = NB * FCH * 64;
    k_convin<<<(n + 255) / 256, 256, 0, stream>>>(feature, convinW, f0);
    k_up<<<(NB * FCH * 256 + 255) / 256, 256, 0, stream>>>(f0, f1, upK + 0, 64);
    k_up<<<(NB * FCH * 1024 + 255) / 256, 256, 0, stream>>>(f1, f2, upK + 9, 256);
    k_up<<<(NB * FCH * 4096 + 255) / 256, 256, 0, stream>>>(f2, f3, upK + 18, 1024);
    k_up_last<<<NB * 256, 256, 0, stream>>>(f3, ffb, upK + 27);

    float* poF = resA;          float* pnF = resB_;
    unsigned short* poH = mirA; unsigned short* pnH = mirB;
    for (int s = 0; s < 4; ++s) {
        int flags = (s == 0 ? 1 : 0) | (s == 3 ? 2 : 0);
        k_stack<<<NB * 128, 512, 0, stream>>>(
            x, firstWT, poF, poH, pnF, pnH, skipF, ffb,
            ATb + (size_t)s * 6 * 128 * 288, SRTb + (size_t)s * 6 * 128 * 64,
            convB + s * 6 * 128, skipB + s * 6 * 64, resB + s * 6 * 64,
            W1b, last1b, W2b, last2b, (float*)d_out, flags);
        float* tf = poF; poF = pnF; pnF = tf;
        unsigned short* th = poH; poH = pnH; pnH = th;
    }
}

// Round 11
// 357.716 us; speedup vs baseline: 2.2112x; 1.1168x over previous
//
#include <hip/hip_runtime.h>
#include <math.h>

#define T_LEN   16384
#define NB      2
#define FCH     80
#define NLAYERS 24
#define TFRAMES 68
#define PAD     88
#define FPAD    104

typedef __attribute__((ext_vector_type(8))) short bf16x8;
typedef __attribute__((ext_vector_type(4))) float f32x4;

static __device__ inline unsigned short f2bf(float f) {
    unsigned int u = __float_as_uint(f);
    unsigned int r = (u + 0x7FFFu + ((u >> 16) & 1u)) >> 16;
    return (unsigned short)r;
}

// ---------------------------------------------------------------------------
// Pack: bf16 weight layouts + firstWT (transposed embedding table, bias folded)
// ---------------------------------------------------------------------------
__global__ void k_pack(const float* __restrict__ convW, const float* __restrict__ condW,
                       const float* __restrict__ skipW, const float* __restrict__ resW,
                       const float* __restrict__ last1W, const float* __restrict__ last2W,
                       const float* __restrict__ firstW, const float* __restrict__ firstb,
                       unsigned short* __restrict__ ATb, unsigned short* __restrict__ SRTb,
                       unsigned short* __restrict__ W1b, unsigned short* __restrict__ W2b,
                       float* __restrict__ firstWT) {
    int idx = blockIdx.x * 256 + threadIdx.x;
    const int nAT = NLAYERS * 128 * 288;
    const int nSR = NLAYERS * 128 * 64;
    const int e0 = nAT, e1 = e0 + nSR, e2 = e1 + 4096, e3 = e2 + 16384, e4 = e3 + 16384;
    if (idx < e0) {
        int k = idx % 288;
        int o = (idx / 288) & 127;
        int l = idx / (288 * 128);
        float v = 0.f;
        if (k < 192) v = convW[(((l * 128 + o) * 64) + (k & 63)) * 3 + (k >> 6)];
        else if (k - 192 < 80) v = condW[(l * 128 + o) * 80 + (k - 192)];
        ATb[idx] = f2bf(v);
    } else if (idx < e1) {
        int j = idx - e0;
        int k = j & 63;
        int o2 = (j >> 6) & 127;
        int l = j / (64 * 128);
        float v = (o2 < 64) ? skipW[(l * 64 + o2) * 64 + k]
                            : resW[(l * 64 + (o2 - 64)) * 64 + k];
        SRTb[j] = f2bf(v);
    } else if (idx < e2) {
        W1b[idx - e1] = f2bf(last1W[idx - e1]);
    } else if (idx < e3) {
        W2b[idx - e2] = f2bf(last2W[idx - e2]);
    } else if (idx < e4) {
        int j = idx - e3;
        int xs = j >> 6, c = j & 63;
        firstWT[j] = firstW[c * 256 + xs] + firstb[c];
    }
}

// ---------------------------------------------------------------------------
// ConvIn: valid conv, kernel 5, (B,80,68) -> (B,80,64)
// ---------------------------------------------------------------------------
__global__ void k_convin(const float* __restrict__ feat, const float* __restrict__ W,
                         float* __restrict__ f0) {
    int idx = blockIdx.x * 256 + threadIdx.x;
    if (idx >= NB * FCH * 64) return;
    int t = idx & 63;
    int o = (idx >> 6) % FCH;
    int b = idx / (64 * FCH);
    const float* fb = feat + b * FCH * TFRAMES;
    const float* wo = W + o * FCH * 5;
    float acc = 0.f;
    for (int i = 0; i < FCH; ++i) {
        const float* fi = fb + i * TFRAMES + t;
        const float* wi = wo + i * 5;
#pragma unroll
        for (int k = 0; k < 5; ++k) acc += fi[k] * wi[k];
    }
    f0[idx] = acc;
}

// ---------------------------------------------------------------------------
// Upsample stage (x4 repeat + 9-tap smooth), fp32 c-major
// ---------------------------------------------------------------------------
__global__ void k_up(const float* __restrict__ in, float* __restrict__ out,
                     const float* __restrict__ kern, int Tin) {
    int Tout = Tin * 4;
    int idx = blockIdx.x * 256 + threadIdx.x;
    if (idx >= NB * FCH * Tout) return;
    int t = idx % Tout;
    int bc = idx / Tout;
    const float* ib = in + bc * Tin;
    float acc = 0.f;
#pragma unroll
    for (int k = 0; k < 9; ++k) {
        int u = t + k - 4;
        if (u >= 0 && u < Tout) acc += kern[k] * ib[u >> 2];
    }
    out[idx] = acc;
}

// ---------------------------------------------------------------------------
// Last upsample -> bf16 TIME-MAJOR [b][t][96], LDS-staged source frames
// ---------------------------------------------------------------------------
__global__ __launch_bounds__(256)
void k_up_last(const float* __restrict__ in, unsigned short* __restrict__ outH,
               const float* __restrict__ kern) {
    __shared__ float sF[18 * 80];
    const int tid = threadIdx.x;
    const int b  = blockIdx.x >> 8;
    const int t0 = (blockIdx.x & 255) * 64;
    const int fr0 = (t0 >> 2) - 1;

    for (int idx = tid; idx < 18 * 80; idx += 256) {
        int c = idx / 18, fr = idx - c * 18;
        int gfr = fr0 + fr;
        float v = 0.f;
        if (gfr >= 0 && gfr < 4096) v = in[((size_t)b * 80 + c) * 4096 + gfr];
        sF[fr * 80 + c] = v;
    }
    float kr[9];
#pragma unroll
    for (int k = 0; k < 9; ++k) kr[k] = kern[k];
    __syncthreads();

    for (int idx = tid; idx < 64 * 96; idx += 256) {
        int c = idx % 96;
        int t = idx / 96;
        float acc = 0.f;
        if (c < 80) {
            int ubase = t0 + t - 4;
#pragma unroll
            for (int k = 0; k < 9; ++k) {
                int fr = ((ubase + k) >> 2) - fr0;
                acc += kr[k] * sF[fr * 80 + c];
            }
        }
        outH[((size_t)b * T_LEN + t0 + t) * 96 + c] = f2bf(acc);
    }
}

// ---------------------------------------------------------------------------
// STACK KERNEL v4: single in-place LDS residual buffer, PAD=88 (16B-aligned
// rows, <=2-way banks), cond features staged to LDS once per block (FPAD=104),
// GEMM1 tile-PAIR processing (4 MFMA chains in flight). 145 KB LDS, 1 blk/CU.
// flags: bit0 = first stack, bit1 = last stack
// ---------------------------------------------------------------------------
__global__ __launch_bounds__(512, 1)
void k_stack(const int* __restrict__ x, const float* __restrict__ firstWT,
             const float* __restrict__ prevF, const unsigned short* __restrict__ prevH,
             float* __restrict__ nextF, unsigned short* __restrict__ nextH,
             float* __restrict__ skipF, const unsigned short* __restrict__ ffb,
             const unsigned short* __restrict__ ATb, const unsigned short* __restrict__ SRTb,
             const float* __restrict__ convB, const float* __restrict__ skipB,
             const float* __restrict__ resB,
             const unsigned short* __restrict__ W1b, const float* __restrict__ b1,
             const unsigned short* __restrict__ W2b, const float* __restrict__ b2,
             float* __restrict__ outp, int flags)
{
    __shared__ __align__(16) unsigned short s_P[264 * PAD];   // residual [row][c]
    __shared__ __align__(16) unsigned short s_Z[256 * PAD];   // z / tail staging
    __shared__ __align__(16) unsigned short s_F[256 * FPAD];  // cond features

    const int tid  = threadIdx.x;
    const int b    = blockIdx.x >> 7;
    const int t0   = (blockIdx.x & 127) * 128;
    const int lane = tid & 63;
    const int wv   = tid >> 6;          // 0..7
    const int col  = lane & 15;
    const int quad = lane >> 4;
    const int pair = wv & 3;            // GEMM1 gate pair
    const int par  = wv >> 2;           // col-tile parity
    const int chA  = 16 * pair + 4 * quad;
    const int srm  = (wv < 4) ? wv : (wv - 4);
    const int chS  = 16 * srm + 4 * quad;
    const bool firstStack = (flags & 1) != 0;
    const bool lastStack  = (flags & 2) != 0;

    const int ts_out[6] = {0, 0, 1, 2, 4, 8};

    // zero margin rows 0..7
    for (int i = tid; i < 8 * (PAD / 2); i += 512) {
        int r = i / (PAD / 2), dw = i - r * (PAD / 2);
        ((unsigned int*)(s_P + r * PAD))[dw] = 0u;
    }
    // stage residual rows 8..263 <- abs cols [t0-128, t0+128)
    if (firstStack) {
        for (int i = tid; i < 256 * 8; i += 512) {
            int r = i >> 3, seg = i & 7;
            int g = t0 - 128 + r;
            bf16x8 v = {0, 0, 0, 0, 0, 0, 0, 0};
            if (g >= 0) {
                int xs = (g == 0) ? 0 : x[b * T_LEN + g - 1];
                const float* p = firstWT + xs * 64 + seg * 8;
                f32x4 a0 = *(const f32x4*)p;
                f32x4 a1 = *(const f32x4*)(p + 4);
                v[0] = (short)f2bf(a0[0]); v[1] = (short)f2bf(a0[1]);
                v[2] = (short)f2bf(a0[2]); v[3] = (short)f2bf(a0[3]);
                v[4] = (short)f2bf(a1[0]); v[5] = (short)f2bf(a1[1]);
                v[6] = (short)f2bf(a1[2]); v[7] = (short)f2bf(a1[3]);
            }
            *(bf16x8*)(s_P + (8 + r) * PAD + seg * 8) = v;
        }
    } else {
        const unsigned short* hb = prevH + (size_t)b * T_LEN * 64;
        for (int i = tid; i < 256 * 8; i += 512) {
            int r = i >> 3, seg = i & 7;
            int g = t0 - 128 + r;
            bf16x8 v = {0, 0, 0, 0, 0, 0, 0, 0};
            if (g >= 0) v = *(const bf16x8*)(hb + (size_t)g * 64 + seg * 8);
            *(bf16x8*)(s_P + (8 + r) * PAD + seg * 8) = v;
        }
    }
    // stage cond features rows 0..255 <- abs cols [t0-128, t0+128), clamped
    {
        const unsigned short* fb = ffb + (size_t)b * T_LEN * 96;
        for (int i = tid; i < 256 * 12; i += 512) {
            int r = i / 12, seg = i - r * 12;
            int g = t0 - 128 + r;
            int gcl = g < 0 ? 0 : g;
            *(bf16x8*)(s_F + r * FPAD + seg * 8) =
                *(const bf16x8*)(fb + (size_t)gcl * 96 + seg * 8);
        }
    }

    // per-wave persistent state
    f32x4 resReg[8];
    f32x4 skipAcc[8];
#pragma unroll
    for (int i = 0; i < 8; ++i) skipAcc[i] = (f32x4){0.f, 0.f, 0.f, 0.f};
    if (wv >= 4) {
        if (firstStack) {
#pragma unroll
            for (int i = 0; i < 8; ++i) {
                int t = t0 + i * 16 + col;
                int xs = (t == 0) ? 0 : x[b * T_LEN + t - 1];
                resReg[i] = *(const f32x4*)(firstWT + xs * 64 + chS);
            }
        } else {
#pragma unroll
            for (int i = 0; i < 8; ++i)
                resReg[i] = *(const f32x4*)(prevF +
                              ((size_t)b * T_LEN + t0 + i * 16 + col) * 64 + chS);
        }
    }
    __syncthreads();

#pragma unroll 1
    for (int l = 0; l < 6; ++l) {
        const int d  = 1 << l;
        const int ts = ts_out[l];

        const unsigned short* AL = ATb + (size_t)l * 128 * 288;
        bf16x8 frA0[9], frA1[9];
#pragma unroll
        for (int ks = 0; ks < 9; ++ks) {
            frA0[ks] = *(const bf16x8*)(AL + (size_t)(16 * pair + col) * 288 + ks * 32 + quad * 8);
            frA1[ks] = *(const bf16x8*)(AL + (size_t)(64 + 16 * pair + col) * 288 + ks * 32 + quad * 8);
        }
        f32x4 cbA = *(const f32x4*)(convB + l * 128 + chA);
        f32x4 cbG = *(const f32x4*)(convB + l * 128 + 64 + chA);

        // ---- GEMM1 + gated activation: tile PAIRS (4 MFMA chains) ----
#pragma unroll
        for (int j = 0; j < 4; ++j) {
            const int tA = par + 4 * j;
            const int tB = tA + 2;
            const bool vA = tA >= ts, vB = tB >= ts;   // wave-uniform
            if (!vA && !vB) continue;
            const int tAc = vA ? tA : ts;
            const int tBc = vB ? tB : ts;
            const int rA = 8 + tAc * 16 + col;
            const int rB = 8 + tBc * 16 + col;
            f32x4 aA0 = (f32x4){0.f, 0.f, 0.f, 0.f};
            f32x4 aA1 = (f32x4){0.f, 0.f, 0.f, 0.f};
            f32x4 aB0 = (f32x4){0.f, 0.f, 0.f, 0.f};
            f32x4 aB1 = (f32x4){0.f, 0.f, 0.f, 0.f};
#pragma unroll
            for (int ks = 0; ks < 6; ++ks) {
                const int off = (ks & 1) * 32 + quad * 8;
                const int sh = -2 * d + (ks >> 1) * d;
                bf16x8 fBA = *(const bf16x8*)(s_P + (rA + sh) * PAD + off);
                bf16x8 fBB = *(const bf16x8*)(s_P + (rB + sh) * PAD + off);
                aA0 = __builtin_amdgcn_mfma_f32_16x16x32_bf16(frA0[ks], fBA, aA0, 0, 0, 0);
                aA1 = __builtin_amdgcn_mfma_f32_16x16x32_bf16(frA1[ks], fBA, aA1, 0, 0, 0);
                aB0 = __builtin_amdgcn_mfma_f32_16x16x32_bf16(frA0[ks], fBB, aB0, 0, 0, 0);
                aB1 = __builtin_amdgcn_mfma_f32_16x16x32_bf16(frA1[ks], fBB, aB1, 0, 0, 0);
            }
#pragma unroll
            for (int ks = 6; ks < 9; ++ks) {
                const int off = (ks - 6) * 32 + quad * 8;
                bf16x8 fFA = *(const bf16x8*)(s_F + (tAc * 16 + col) * FPAD + off);
                bf16x8 fFB = *(const bf16x8*)(s_F + (tBc * 16 + col) * FPAD + off);
                aA0 = __builtin_amdgcn_mfma_f32_16x16x32_bf16(frA0[ks], fFA, aA0, 0, 0, 0);
                aA1 = __builtin_amdgcn_mfma_f32_16x16x32_bf16(frA1[ks], fFA, aA1, 0, 0, 0);
                aB0 = __builtin_amdgcn_mfma_f32_16x16x32_bf16(frA0[ks], fFB, aB0, 0, 0, 0);
                aB1 = __builtin_amdgcn_mfma_f32_16x16x32_bf16(frA1[ks], fFB, aB1, 0, 0, 0);
            }
#pragma unroll
            for (int half = 0; half < 2; ++half) {
                const bool vv = half ? vB : vA;
                if (!vv) continue;
                const int tl = half ? tB : tA;
                f32x4 a0 = half ? aB0 : aA0;
                f32x4 a1 = half ? aB1 : aA1;
                unsigned int pk[2];
#pragma unroll
                for (int r2 = 0; r2 < 2; ++r2) {
                    float zz[2];
#pragma unroll
                    for (int e = 0; e < 2; ++e) {
                        float av = a0[2 * r2 + e] + cbA[2 * r2 + e];
                        float gv = a1[2 * r2 + e] + cbG[2 * r2 + e];
                        float th = 1.f - 2.f * __builtin_amdgcn_rcpf(__expf(2.f * av) + 1.f);
                        float sg = __builtin_amdgcn_rcpf(1.f + __expf(-gv));
                        zz[e] = th * sg;
                    }
                    pk[r2] = (unsigned int)f2bf(zz[0]) | ((unsigned int)f2bf(zz[1]) << 16);
                }
                unsigned int* zp = (unsigned int*)(s_Z + (tl * 16 + col) * PAD + chA);
                zp[0] = pk[0];
                zp[1] = pk[1];
            }
        }
        __syncthreads();

        // ---- GEMM2: skip waves = owned skip; res waves = halo RMW + owned ----
        const unsigned short* SL = SRTb + (size_t)l * 128 * 64;
        if (wv < 4) {
            bf16x8 wk0 = *(const bf16x8*)(SL + (size_t)(16 * srm + col) * 64 + quad * 8);
            bf16x8 wk1 = *(const bf16x8*)(SL + (size_t)(16 * srm + col) * 64 + 32 + quad * 8);
            f32x4 sb4 = *(const f32x4*)(skipB + l * 64 + chS);
#pragma unroll
            for (int i = 0; i < 8; ++i) {
                const int zr = ((8 + i) * 16 + col) * PAD;
                bf16x8 fz0 = *(const bf16x8*)(s_Z + zr + quad * 8);
                bf16x8 fz1 = *(const bf16x8*)(s_Z + zr + 32 + quad * 8);
                f32x4 s = (f32x4){0.f, 0.f, 0.f, 0.f};
                s = __builtin_amdgcn_mfma_f32_16x16x32_bf16(wk0, fz0, s, 0, 0, 0);
                s = __builtin_amdgcn_mfma_f32_16x16x32_bf16(wk1, fz1, s, 0, 0, 0);
#pragma unroll
                for (int e = 0; e < 4; ++e) skipAcc[i][e] += s[e] + sb4[e];
            }
        } else {
            bf16x8 wr0 = *(const bf16x8*)(SL + (size_t)(64 + 16 * srm + col) * 64 + quad * 8);
            bf16x8 wr1 = *(const bf16x8*)(SL + (size_t)(64 + 16 * srm + col) * 64 + 32 + quad * 8);
            f32x4 rb4 = *(const f32x4*)(resB + l * 64 + chS);
            // halo tiles: in-place RMW of s_P (unrolled, runtime uniform guard)
#pragma unroll
            for (int tl = 0; tl < 8; ++tl) {
                if (tl < ts) continue;
                const int zr = (tl * 16 + col) * PAD;
                bf16x8 fz0 = *(const bf16x8*)(s_Z + zr + quad * 8);
                bf16x8 fz1 = *(const bf16x8*)(s_Z + zr + 32 + quad * 8);
                const int row = 8 + tl * 16 + col;
                unsigned int* pv = (unsigned int*)(s_P + row * PAD + chS);
                unsigned int w0 = pv[0], w1 = pv[1];
                f32x4 acc;
                acc[0] = __uint_as_float(w0 << 16);
                acc[1] = __uint_as_float(w0 & 0xFFFF0000u);
                acc[2] = __uint_as_float(w1 << 16);
                acc[3] = __uint_as_float(w1 & 0xFFFF0000u);
                acc = __builtin_amdgcn_mfma_f32_16x16x32_bf16(wr0, fz0, acc, 0, 0, 0);
                acc = __builtin_amdgcn_mfma_f32_16x16x32_bf16(wr1, fz1, acc, 0, 0, 0);
#pragma unroll
                for (int e = 0; e < 4; ++e) acc[e] += rb4[e];
                int g = t0 - 128 + tl * 16 + col;
                if (g < 0) acc = (f32x4){0.f, 0.f, 0.f, 0.f};
                pv[0] = (unsigned int)f2bf(acc[0]) | ((unsigned int)f2bf(acc[1]) << 16);
                pv[1] = (unsigned int)f2bf(acc[2]) | ((unsigned int)f2bf(acc[3]) << 16);
            }
            // owned tiles
            if (!(lastStack && l == 5)) {
#pragma unroll
                for (int i = 0; i < 8; ++i) {
                    const int zr = ((8 + i) * 16 + col) * PAD;
                    bf16x8 fz0 = *(const bf16x8*)(s_Z + zr + quad * 8);
                    bf16x8 fz1 = *(const bf16x8*)(s_Z + zr + 32 + quad * 8);
                    f32x4 acc = resReg[i];
                    acc = __builtin_amdgcn_mfma_f32_16x16x32_bf16(wr0, fz0, acc, 0, 0, 0);
                    acc = __builtin_amdgcn_mfma_f32_16x16x32_bf16(wr1, fz1, acc, 0, 0, 0);
#pragma unroll
                    for (int e = 0; e < 4; ++e) acc[e] += rb4[e];
                    resReg[i] = acc;
                    if (l < 5) {
                        const int row = 8 + (8 + i) * 16 + col;
                        unsigned int* qp = (unsigned int*)(s_P + row * PAD + chS);
                        qp[0] = (unsigned int)f2bf(acc[0]) | ((unsigned int)f2bf(acc[1]) << 16);
                        qp[1] = (unsigned int)f2bf(acc[2]) | ((unsigned int)f2bf(acc[3]) << 16);
                    }
                }
            }
        }
        __syncthreads();
    }

    // ---------------- epilogue ----------------
    if (!lastStack) {
        if (wv >= 4) {
#pragma unroll
            for (int i = 0; i < 8; ++i) {
                size_t base = ((size_t)b * T_LEN + t0 + i * 16 + col) * 64 + chS;
                *(f32x4*)(nextF + base) = resReg[i];
                unsigned int p01 = (unsigned int)f2bf(resReg[i][0]) | ((unsigned int)f2bf(resReg[i][1]) << 16);
                unsigned int p23 = (unsigned int)f2bf(resReg[i][2]) | ((unsigned int)f2bf(resReg[i][3]) << 16);
                unsigned int* hp = (unsigned int*)(nextH + base);
                hp[0] = p01;
                hp[1] = p23;
            }
        } else {
#pragma unroll
            for (int i = 0; i < 8; ++i) {
                size_t base = ((size_t)b * T_LEN + t0 + i * 16 + col) * 64 + chS;
                if (firstStack) {
                    *(f32x4*)(skipF + base) = skipAcc[i];
                } else {
                    f32x4 s = *(const f32x4*)(skipF + base);
#pragma unroll
                    for (int e = 0; e < 4; ++e) s[e] += skipAcc[i][e];
                    *(f32x4*)(skipF + base) = s;
                }
            }
        }
        return;
    }

    // ---------------- fused tail (last stack) ----------------
    unsigned short* s_S = s_Z;
    unsigned short* s_H = s_Z + 128 * PAD;
    if (wv < 4) {
#pragma unroll
        for (int i = 0; i < 8; ++i) {
            size_t base = ((size_t)b * T_LEN + t0 + i * 16 + col) * 64 + chS;
            f32x4 s = *(const f32x4*)(skipF + base);
            float v0 = fmaxf(s[0] + skipAcc[i][0], 0.f);
            float v1 = fmaxf(s[1] + skipAcc[i][1], 0.f);
            float v2 = fmaxf(s[2] + skipAcc[i][2], 0.f);
            float v3 = fmaxf(s[3] + skipAcc[i][3], 0.f);
            unsigned int* sp = (unsigned int*)(s_S + (i * 16 + col) * PAD + chS);
            sp[0] = (unsigned int)f2bf(v0) | ((unsigned int)f2bf(v1) << 16);
            sp[1] = (unsigned int)f2bf(v2) | ((unsigned int)f2bf(v3) << 16);
        }
    }
    __syncthreads();

    // last1: h2 = relu(W1 @ relu(skip) + b1)
    {
        const int m1 = wv & 3;
        const int q1 = wv >> 2;
        bf16x8 fw0 = *(const bf16x8*)(W1b + (size_t)(16 * m1 + col) * 64 + quad * 8);
        bf16x8 fw1 = *(const bf16x8*)(W1b + (size_t)(16 * m1 + col) * 64 + 32 + quad * 8);
        f32x4 bb1 = *(const f32x4*)(b1 + 16 * m1 + 4 * quad);
#pragma unroll
        for (int i = 0; i < 8; ++i) {
            if ((i & 1) != q1) continue;
            const int zr = (i * 16 + col) * PAD;
            bf16x8 fz0 = *(const bf16x8*)(s_S + zr + quad * 8);
            bf16x8 fz1 = *(const bf16x8*)(s_S + zr + 32 + quad * 8);
            f32x4 a = (f32x4){0.f, 0.f, 0.f, 0.f};
            a = __builtin_amdgcn_mfma_f32_16x16x32_bf16(fw0, fz0, a, 0, 0, 0);
            a = __builtin_amdgcn_mfma_f32_16x16x32_bf16(fw1, fz1, a, 0, 0, 0);
            float h0 = fmaxf(a[0] + bb1[0], 0.f), h1 = fmaxf(a[1] + bb1[1], 0.f);
            float h2 = fmaxf(a[2] + bb1[2], 0.f), h3 = fmaxf(a[3] + bb1[3], 0.f);
            unsigned int* hp = (unsigned int*)(s_H + (i * 16 + col) * PAD + 16 * m1 + 4 * quad);
            hp[0] = (unsigned int)f2bf(h0) | ((unsigned int)f2bf(h1) << 16);
            hp[1] = (unsigned int)f2bf(h2) | ((unsigned int)f2bf(h3) << 16);
        }
    }
    __syncthreads();

    // last2: out = W2 @ h2 + b2  (fp32 c-major)
#pragma unroll
    for (int p2 = 0; p2 < 2; ++p2) {
        const int m2 = wv + 8 * p2;
        bf16x8 fw0 = *(const bf16x8*)(W2b + (size_t)(16 * m2 + col) * 64 + quad * 8);
        bf16x8 fw1 = *(const bf16x8*)(W2b + (size_t)(16 * m2 + col) * 64 + 32 + quad * 8);
        f32x4 bb2 = *(const f32x4*)(b2 + 16 * m2 + 4 * quad);
#pragma unroll
        for (int i = 0; i < 8; ++i) {
            const int zr = (i * 16 + col) * PAD;
            bf16x8 fz0 = *(const bf16x8*)(s_H + zr + quad * 8);
            bf16x8 fz1 = *(const bf16x8*)(s_H + zr + 32 + quad * 8);
            f32x4 a = (f32x4){0.f, 0.f, 0.f, 0.f};
            a = __builtin_amdgcn_mfma_f32_16x16x32_bf16(fw0, fz0, a, 0, 0, 0);
            a = __builtin_amdgcn_mfma_f32_16x16x32_bf16(fw1, fz1, a, 0, 0, 0);
            int t = t0 + i * 16 + col;
            int o0 = 16 * m2 + 4 * quad;
#pragma unroll
            for (int e = 0; e < 4; ++e)
                outp[((size_t)b * 256 + o0 + e) * T_LEN + t] = a[e] + bb2[e];
        }
    }
}

// ---------------------------------------------------------------------------
extern "C" void kernel_launch(void* const* d_in, const int* in_sizes, int n_in,
                              void* d_out, int out_size, void* d_ws, size_t ws_size,
                              hipStream_t stream) {
    const int*   x       = (const int*)  d_in[0];
    const float* feature = (const float*)d_in[1];
    const float* firstW  = (const float*)d_in[2];
    const float* firstb  = (const float*)d_in[3];
    const float* convW   = (const float*)d_in[4];
    const float* convB   = (const float*)d_in[5];
    const float* condW   = (const float*)d_in[6];
    const float* skipW   = (const float*)d_in[7];
    const float* skipB   = (const float*)d_in[8];
    const float* resW    = (const float*)d_in[9];
    const float* resB    = (const float*)d_in[10];
    const float* last1W  = (const float*)d_in[11];
    const float* last1b  = (const float*)d_in[12];
    const float* last2W  = (const float*)d_in[13];
    const float* last2b  = (const float*)d_in[14];
    const float* convinW = (const float*)d_in[15];
    const float* upK     = (const float*)d_in[16];

    float* ws = (float*)d_ws;
    float* f0      = ws;                       // 10240
    float* f1      = f0 + 10240;               // 40960
    float* f2      = f1 + 40960;               // 163840
    float* f3      = f2 + 163840;              // 655360
    float* firstWT = f3 + 655360;              // 16384
    float* resA    = firstWT + 16384;          // 2097152
    float* resB_   = resA + 2097152;           // 2097152
    float* skipF   = resB_ + 2097152;          // 2097152
    unsigned short* mirA = (unsigned short*)(skipF + 2097152);  // 2097152
    unsigned short* mirB = mirA + 2097152;                      // 2097152
    unsigned short* ffb  = mirB + 2097152;                      // 3145728
    unsigned short* ATb  = ffb + 3145728;                       // 884736
    unsigned short* SRTb = ATb + 884736;                        // 196608
    unsigned short* W1b  = SRTb + 196608;                       // 4096
    unsigned short* W2b  = W1b + 4096;                          // 16384

    int n;
    n = NLAYERS * 128 * 288 + NLAYERS * 128 * 64 + 4096 + 16384 + 16384;
    k_pack<<<(n + 255) / 256, 256, 0, stream>>>(convW, condW, skipW, resW, last1W, last2W,
                                                firstW, firstb, ATb, SRTb, W1b, W2b, firstWT);
    n = NB * FCH * 64;
    k_convin<<<(n + 255) / 256, 256, 0, stream>>>(feature, convinW, f0);
    k_up<<<(NB * FCH * 256 + 255) / 256, 256, 0, stream>>>(f0, f1, upK + 0, 64);
    k_up<<<(NB * FCH * 1024 + 255) / 256, 256, 0, stream>>>(f1, f2, upK + 9, 256);
    k_up<<<(NB * FCH * 4096 + 255) / 256, 256, 0, stream>>>(f2, f3, upK + 18, 1024);
    k_up_last<<<NB * 256, 256, 0, stream>>>(f3, ffb, upK + 27);

    float* poF = resA;          float* pnF = resB_;
    unsigned short* poH = mirA; unsigned short* pnH = mirB;
    for (int s = 0; s < 4; ++s) {
        int flags = (s == 0 ? 1 : 0) | (s == 3 ? 2 : 0);
        k_stack<<<NB * 128, 512, 0, stream>>>(
            x, firstWT, poF, poH, pnF, pnH, skipF, ffb,
            ATb + (size_t)s * 6 * 128 * 288, SRTb + (size_t)s * 6 * 128 * 64,
            convB + s * 6 * 128, skipB + s * 6 * 64, resB + s * 6 * 64,
            W1b, last1b, W2b, last2b, (float*)d_out, flags);
        float* tf = poF; poF = pnF; pnF = tf;
        unsigned short* th = poH; poH = pnH; pnH = th;
    }
}